// Round 1
// baseline (314.869 us; speedup 1.0000x reference)
//
#include <hip/hip_runtime.h>

// NoTradeRegionRNN: T=512, B=65536, H=I=1.
// Every per-step op collapses to scalar math per batch element; the only
// coupling is the sequential recurrence in t. One thread per batch element,
// coalesced over b, depth-7 register prefetch pipeline (511 = 7*73 so the
// unrolled slot index is always compile-time constant -> stays in VGPRs).

#define T_STEPS 512
#define BATCH   65536
#define PF      7   // prefetch depth; 511 = 7 * 73

__global__ __launch_bounds__(256, 1)
void notrade_rnn_kernel(const float* __restrict__ input,    // [T, B]
                        const float* __restrict__ target,   // [1]
                        const float* __restrict__ returns,  // [T-1, B]
                        const float* __restrict__ W_in,     // [1]
                        const float* __restrict__ W_h,      // [1]
                        const float* __restrict__ b_h,      // [1]
                        const float* __restrict__ W_fc1,    // [1]
                        const float* __restrict__ W_fc2,    // [1]
                        float* __restrict__ out)            // [T*B] output, then [B] h_final
{
    const int b = blockIdx.x * blockDim.x + threadIdx.x;

    // Scalar parameters (uniform across lanes; L2-broadcast loads).
    const float pi  = target[0];
    const float win = W_in[0];
    const float wh  = W_h[0];
    const float bh  = b_h[0];
    const float wf1 = W_fc1[0];
    const float wf2 = W_fc2[0];
    const float c1  = bh - pi;        // ingate  = win*x + wh*h_adj + c1
    const float c2  = 2.0f * bh;      // ingate2 = wf1*relu(ingate) + c2
    const float c3  = pi + bh;        // h_new   = wf2*relu(ingate2) + c3

    // t = 0: h0 = input[0]
    float h = input[b];
    out[b] = h;

    // Register prefetch pipeline: slot i holds x for t = tbase+i and
    // r for t-1 = tbase+i-1. All indices compile-time constant.
    float xs[PF], rs[PF];
#pragma unroll
    for (int i = 0; i < PF; ++i) {
        xs[i] = input[(1 + i) * BATCH + b];
        rs[i] = returns[i * BATCH + b];
    }

    for (int c = 0; c < (T_STEPS - 1) / PF; ++c) {
        const int tbase = 1 + c * PF;
#pragma unroll
        for (int i = 0; i < PF; ++i) {
            const float x = xs[i];
            const float r = rs[i];

            // Prefetch the same slot for the next chunk (7 iterations ahead).
            const int tn = tbase + PF + i;
            if (tn < T_STEPS) {
                xs[i] = input[tn * BATCH + b];
                rs[i] = returns[(tn - 1) * BATCH + b];
            }

            // Recurrence (precise f32 division: memory-bound, div is free).
            const float h_adj = h * (1.0f + r) / fmaf(h, r, 1.0f);
            const float ing   = fmaf(win, x, fmaf(wh, h_adj, c1));
            const float ing2  = fmaf(wf1, fmaxf(ing, 0.0f), c2);
            h = fmaf(wf2, fmaxf(ing2, 0.0f), c3);

            out[(tbase + i) * BATCH + b] = h;
        }
    }

    // h_final, appended after the [T, B] output block.
    out[T_STEPS * BATCH + b] = h;
}

extern "C" void kernel_launch(void* const* d_in, const int* in_sizes, int n_in,
                              void* d_out, int out_size, void* d_ws, size_t ws_size,
                              hipStream_t stream)
{
    // setup_inputs() order: input, target, returns, hidden(unused),
    //                       W_in, W_h, b_h, W_fc1, W_fc2
    const float* input   = (const float*)d_in[0];
    const float* target  = (const float*)d_in[1];
    const float* returns = (const float*)d_in[2];
    const float* W_in    = (const float*)d_in[4];
    const float* W_h     = (const float*)d_in[5];
    const float* b_h     = (const float*)d_in[6];
    const float* W_fc1   = (const float*)d_in[7];
    const float* W_fc2   = (const float*)d_in[8];
    float* out = (float*)d_out;

    dim3 grid(BATCH / 256), block(256);
    hipLaunchKernelGGL(notrade_rnn_kernel, grid, block, 0, stream,
                       input, target, returns, W_in, W_h, b_h, W_fc1, W_fc2, out);
}